// Round 4
// baseline (1561.254 us; speedup 1.0000x reference)
//
#include <hip/hip_runtime.h>
#include <stdint.h>

#define B_ 4
#define H_ 16
#define S_ 2048
#define D_ 64
#define QBLK 32
#define NTHREADS 512
#define NWIN 16                      /* 32-k windows per 512-k slab */

typedef __attribute__((ext_vector_type(8))) short short8;
typedef __attribute__((ext_vector_type(4))) float float4v;
typedef __attribute__((ext_vector_type(4))) unsigned int uint4v;

static __device__ __forceinline__ short f2bf(float f) {
  uint32_t u = __builtin_bit_cast(uint32_t, f);
  u = (u + 0x7FFFu + ((u >> 16) & 1u)) >> 16;   // RNE
  return (short)u;
}
static __device__ __forceinline__ float bf2f(short s) {
  uint32_t u = ((uint32_t)(uint16_t)s) << 16;
  return __builtin_bit_cast(float, u);
}
static __device__ __forceinline__ uint32_t packbf(float lo, float hi) {
  return ((uint32_t)(uint16_t)f2bf(hi) << 16) | (uint16_t)f2bf(lo);
}
// nonzero-byte indicator bits at 0,8,16,24
static __device__ __forceinline__ uint32_t nz4(uint32_t d) {
  uint32_t x = (d & 0x7F7F7F7Fu) + 0x7F7F7F7Fu;
  x = (x | d) & 0x80808080u;
  return x >> 7;
}
static __device__ __forceinline__ uint32_t nib(uint32_t d) {
  return ((nz4(d) * 0x01020408u) >> 24) & 0xFu;
}

#define KBF_BYTES ((size_t)64 * S_ * D_ * 2)
#define VT_BYTES  ((size_t)64 * S_ * D_ * 2)

__global__ void detect_mask_dtype(const uint8_t* __restrict__ m, uint32_t* flag) {
  uint32_t a = 0, b = 0;
  for (int i = threadIdx.x; i < 65536; i += 256) {
    uint8_t x = m[i];
    if (i & 3) a |= x; else b |= x;
  }
  uint32_t bits = (a ? 1u : 0u) | (b ? 2u : 0u);
  if (bits) atomicOr(flag, bits);
}

__global__ __launch_bounds__(256) void prep_k(const float* __restrict__ K,
                                              short* __restrict__ Kbf) {
  size_t base = ((size_t)blockIdx.x * 256 + threadIdx.x) * 8;
  float4v a = __builtin_nontemporal_load((const float4v*)(K + base));
  float4v b = __builtin_nontemporal_load((const float4v*)(K + base + 4));
  short8 o;
  o[0]=f2bf(a.x); o[1]=f2bf(a.y); o[2]=f2bf(a.z); o[3]=f2bf(a.w);
  o[4]=f2bf(b.x); o[5]=f2bf(b.y); o[6]=f2bf(b.z); o[7]=f2bf(b.w);
  *(short8*)(Kbf + base) = o;
}

__global__ __launch_bounds__(256) void prep_vt(const float* __restrict__ V,
                                               short* __restrict__ VT) {
  __shared__ short tile[64][72];
  int bh = blockIdx.x >> 5, k0 = (blockIdx.x & 31) * 64;
  const float* src = V + ((size_t)bh * S_ + k0) * D_;
  int t = threadIdx.x;
  int r = t >> 2, c0 = (t & 3) * 16;
#pragma unroll
  for (int j = 0; j < 4; ++j) {
    float4v f = __builtin_nontemporal_load((const float4v*)(src + (size_t)r * D_ + c0 + j * 4));
    tile[r][c0 + j*4 + 0] = f2bf(f.x);
    tile[r][c0 + j*4 + 1] = f2bf(f.y);
    tile[r][c0 + j*4 + 2] = f2bf(f.z);
    tile[r][c0 + j*4 + 3] = f2bf(f.w);
  }
  __syncthreads();
  int d = t >> 2, ks0 = (t & 3) * 16;
  short* dst = VT + (size_t)bh * D_ * S_ + (size_t)d * S_ + k0 + ks0;
#pragma unroll
  for (int half = 0; half < 2; ++half) {
    short8 o;
#pragma unroll
    for (int i = 0; i < 8; ++i) o[i] = tile[ks0 + half * 8 + i][d];
    *(short8*)(dst + half * 8) = o;
  }
}

template <int PREP>
__global__ __launch_bounds__(NTHREADS, 4) void attn_fused(
    const float* __restrict__ Q, const float* __restrict__ K,
    const float* __restrict__ V, const float* __restrict__ scale_p,
    const uint8_t* __restrict__ M, const uint32_t* __restrict__ flag,
    const short* __restrict__ Kbf, const short* __restrict__ VT,
    float* __restrict__ outC, float* __restrict__ outA)
{
  __shared__ uint32_t mbits[QBLK * 65];        // bit k of word: masked
  __shared__ float lsum[QBLK];
  __shared__ float linv[QBLK];
  __shared__ float cbuf[QBLK * 65];            // [q][dd] padded
  __shared__ float tiles[8 * 16 * 33];         // per-wave store-transpose tile

  // XCD-chunked bijective swizzle (4096 blocks, 8 XCDs)
  const int bx  = (blockIdx.x & 7) * 512 + (blockIdx.x >> 3);
  const int bh  = bx >> 6;                     // 64 q-tiles per (b,h)
  const int q0  = (bx & 63) * QBLK;

  const int tid  = threadIdx.x;
  const int w    = tid >> 6;
  const int lane = tid & 63;
  const int g    = lane >> 4;                  // 0..3
  const int c    = lane & 15;                  // 0..15
  const int qg   = w >> 2;                     // q-group 0..1 (16 rows each)
  const int kw   = w & 3;                      // k-slab 0..3 (512 wide)
  const int kslab0 = kw * 512;

  const float scale = scale_p[0];
  const uint32_t fl = flag[0];

  const float* Qp = Q + (size_t)bh * S_ * D_;
  const short* Kbp = Kbf + (size_t)bh * S_ * D_;
  const short* VTp = VT + (size_t)bh * D_ * S_;
  const float* Kfp = K + (size_t)bh * S_ * D_;
  const float* Vfp = V + (size_t)bh * S_ * D_;

  // ---- prologue: mask bitmap + zero reductions ----
  {
    const int row = tid >> 4;                  // 0..31
    const int wq  = tid & 15;                  // covers words wq*4..wq*4+3
    if (fl == 3u) {                            // byte mask
      const uint8_t* mrow = M + ((size_t)bh * S_ + q0 + row) * (size_t)S_ + wq * 128;
#pragma unroll
      for (int j = 0; j < 4; ++j) {
        uint4v a = __builtin_nontemporal_load((const uint4v*)(mrow + j * 32));
        uint4v b = __builtin_nontemporal_load((const uint4v*)(mrow + j * 32 + 16));
        uint32_t bits = nib(a.x) | (nib(a.y) << 4) | (nib(a.z) << 8)  | (nib(a.w) << 12)
                      | (nib(b.x) << 16) | (nib(b.y) << 20) | (nib(b.z) << 24) | (nib(b.w) << 28);
        mbits[row * 65 + wq * 4 + j] = bits;
      }
    } else {                                   // 4-byte mask (int32 / float32)
      const uint32_t* mrow = (const uint32_t*)M + ((size_t)bh * S_ + q0 + row) * (size_t)S_ + wq * 128;
#pragma unroll
      for (int j = 0; j < 4; ++j) {
        uint32_t bits = 0;
#pragma unroll
        for (int u = 0; u < 8; ++u) {
          uint4v wv = __builtin_nontemporal_load((const uint4v*)(mrow + j * 32 + u * 4));
          uint32_t nzb = (wv.x ? 1u : 0u) | (wv.y ? 2u : 0u) | (wv.z ? 4u : 0u) | (wv.w ? 8u : 0u);
          bits |= nzb << (u * 4);
        }
        mbits[row * 65 + wq * 4 + j] = bits;
      }
    }
    for (int i = tid; i < QBLK * 65; i += NTHREADS) cbuf[i] = 0.0f;
    if (tid < QBLK) lsum[tid] = 0.0f;
  }
  __syncthreads();

  // ---- Q as B-frag: lane holds Q[q0+qg*16+c][d chunks] ----
  const int qrow = q0 + qg * 16 + c;
  short8 qB[2];
#pragma unroll
  for (int h = 0; h < 2; ++h) {
    const float* qr = Qp + (size_t)qrow * D_ + h * 32 + g * 8;
    float4v a = *(const float4v*)qr;
    float4v b = *(const float4v*)(qr + 4);
    short8 f;
    f[0]=f2bf(a.x); f[1]=f2bf(a.y); f[2]=f2bf(a.z); f[3]=f2bf(a.w);
    f[4]=f2bf(b.x); f[5]=f2bf(b.y); f[6]=f2bf(b.z); f[7]=f2bf(b.w);
    qB[h] = f;
  }

  const uint32_t* mrowp = &mbits[(qg * 16 + c) * 65 + (kslab0 >> 5)];
  const int srcA = ((2 * g) & 3) * 16 + c;
  const int srcB = srcA + 16;
  const bool hi = g >= 2;

  float rsv = 0.0f;
  float4v cacc[4];
#pragma unroll
  for (int nd = 0; nd < 4; ++nd) cacc[nd] = (float4v){0.f, 0.f, 0.f, 0.f};
  uint32_t es[NWIN][4];

  // ---- phase 1: swapped QK^T -> E in regs -> shuffle -> PV ----
#pragma unroll
  for (int win = 0; win < NWIN; ++win) {
    const int kwin = kslab0 + win * 32;
    float4v acc[2];
    acc[0] = (float4v){0.f,0.f,0.f,0.f};
    acc[1] = (float4v){0.f,0.f,0.f,0.f};
#pragma unroll
    for (int nb = 0; nb < 2; ++nb) {
      short8 a0, a1;
      if (PREP) {
        const short* kr = Kbp + (size_t)(kwin + nb * 16 + c) * D_ + g * 8;
        a0 = *(const short8*)kr;
        a1 = *(const short8*)(kr + 32);
      } else {
        const float* kr = Kfp + (size_t)(kwin + nb * 16 + c) * D_ + g * 8;
        float4v x0 = *(const float4v*)kr,        x1 = *(const float4v*)(kr + 4);
        float4v y0 = *(const float4v*)(kr + 32), y1 = *(const float4v*)(kr + 36);
        a0[0]=f2bf(x0.x); a0[1]=f2bf(x0.y); a0[2]=f2bf(x0.z); a0[3]=f2bf(x0.w);
        a0[4]=f2bf(x1.x); a0[5]=f2bf(x1.y); a0[6]=f2bf(x1.z); a0[7]=f2bf(x1.w);
        a1[0]=f2bf(y0.x); a1[1]=f2bf(y0.y); a1[2]=f2bf(y0.z); a1[3]=f2bf(y0.w);
        a1[4]=f2bf(y1.x); a1[5]=f2bf(y1.y); a1[6]=f2bf(y1.z); a1[7]=f2bf(y1.w);
      }
      acc[nb] = __builtin_amdgcn_mfma_f32_16x16x32_bf16(a0, qB[0], acc[nb], 0, 0, 0);
      acc[nb] = __builtin_amdgcn_mfma_f32_16x16x32_bf16(a1, qB[1], acc[nb], 0, 0, 0);
    }
    // mask + exp (lane's q = c; k = kwin + nb*16 + 4g + r)
    const uint32_t mw = mrowp[win];
    float ev[2][4];
#pragma unroll
    for (int nb = 0; nb < 2; ++nb)
#pragma unroll
      for (int r = 0; r < 4; ++r) {
        const uint32_t bit = (mw >> (nb * 16 + 4 * g + r)) & 1u;
        float e = bit ? 1.0f : __expf(acc[nb][r] * scale);
        ev[nb][r] = e;
        rsv += e;
      }
    es[win][0] = packbf(ev[0][0], ev[0][1]);
    es[win][1] = packbf(ev[0][2], ev[0][3]);
    es[win][2] = packbf(ev[1][0], ev[1][1]);
    es[win][3] = packbf(ev[1][2], ev[1][3]);

    // shuffle-transpose: B2-frag lane(g,c) = E[q=c][k = kwin + g*8 + 0..7]
    uint32_t x0 = __shfl(es[win][0], srcA), y0 = __shfl(es[win][2], srcA);
    uint32_t x1 = __shfl(es[win][1], srcA), y1 = __shfl(es[win][3], srcA);
    uint32_t x2 = __shfl(es[win][0], srcB), y2 = __shfl(es[win][2], srcB);
    uint32_t x3 = __shfl(es[win][1], srcB), y3 = __shfl(es[win][3], srcB);
    uint4v bb;
    bb.x = hi ? y0 : x0;
    bb.y = hi ? y1 : x1;
    bb.z = hi ? y2 : x2;
    bb.w = hi ? y3 : x3;
    const short8 bfrag = __builtin_bit_cast(short8, bb);

    // PV: C^T partial, A = V^T
#pragma unroll
    for (int nd = 0; nd < 4; ++nd) {
      short8 vA;
      if (PREP) {
        vA = *(const short8*)&VTp[(size_t)(nd * 16 + c) * S_ + kwin + g * 8];
      } else {
        const float* vc = Vfp + (size_t)(kwin + g * 8) * D_ + nd * 16 + c;
#pragma unroll
        for (int e = 0; e < 8; ++e) vA[e] = f2bf(vc[(size_t)e * D_]);
      }
      cacc[nd] = __builtin_amdgcn_mfma_f32_16x16x32_bf16(vA, bfrag, cacc[nd], 0, 0, 0);
    }
  }

  // ---- reductions ----
  rsv += __shfl_xor(rsv, 16);
  rsv += __shfl_xor(rsv, 32);
  if (lane < 16) atomicAdd(&lsum[qg * 16 + lane], rsv);
#pragma unroll
  for (int nd = 0; nd < 4; ++nd)
#pragma unroll
    for (int r = 0; r < 4; ++r)
      atomicAdd(&cbuf[(qg * 16 + c) * 65 + nd * 16 + 4 * g + r], cacc[nd][r]);
  __syncthreads();

  if (tid < QBLK) linv[tid] = 1.0f / lsum[tid];
  __syncthreads();

  // ---- context write ----
  {
    const int row = tid >> 4, d0 = (tid & 15) * 4;
    const float inv = linv[row];
    float4v cv;
    cv.x = cbuf[row * 65 + d0 + 0] * inv;
    cv.y = cbuf[row * 65 + d0 + 1] * inv;
    cv.z = cbuf[row * 65 + d0 + 2] * inv;
    cv.w = cbuf[row * 65 + d0 + 3] * inv;
    __builtin_nontemporal_store(cv, (float4v*)&outC[((size_t)bh * S_ + q0 + row) * D_ + d0]);
  }

  // ---- phase 2: normalized attention stores (per-wave LDS transpose) ----
  const float linvq = linv[qg * 16 + c];
  float* tile = &tiles[w * (16 * 33)];
  float* arowbase = outA + ((size_t)bh * S_ + q0 + qg * 16) * (size_t)S_ + kslab0;
#pragma unroll
  for (int win = 0; win < NWIN; ++win) {
#pragma unroll
    for (int nb = 0; nb < 2; ++nb) {
      const uint32_t plo = es[win][nb * 2], phi = es[win][nb * 2 + 1];
      float* tr = &tile[c * 33 + nb * 16 + 4 * g];
      tr[0] = bf2f((short)(plo & 0xffff)) * linvq;
      tr[1] = bf2f((short)(plo >> 16))    * linvq;
      tr[2] = bf2f((short)(phi & 0xffff)) * linvq;
      tr[3] = bf2f((short)(phi >> 16))    * linvq;
    }
#pragma unroll
    for (int s = 0; s < 2; ++s) {
      const int row = s * 8 + (lane >> 3);
      const int col = (lane & 7) * 4;
      float4v v;
      v.x = tile[row * 33 + col + 0];
      v.y = tile[row * 33 + col + 1];
      v.z = tile[row * 33 + col + 2];
      v.w = tile[row * 33 + col + 3];
      __builtin_nontemporal_store(v, (float4v*)&arowbase[(size_t)row * S_ + win * 32 + col]);
    }
  }
}

extern "C" void kernel_launch(void* const* d_in, const int* in_sizes, int n_in,
                              void* d_out, int out_size, void* d_ws, size_t ws_size,
                              hipStream_t stream) {
  const float*   Q     = (const float*)d_in[0];
  const float*   K     = (const float*)d_in[1];
  const float*   V     = (const float*)d_in[2];
  const float*   scale = (const float*)d_in[3];
  const uint8_t* M     = (const uint8_t*)d_in[4];
  uint32_t* flag = (uint32_t*)d_ws;
  float* outC = (float*)d_out;
  float* outA = outC + (size_t)B_ * H_ * S_ * D_;

  hipMemsetAsync(flag, 0, 4, stream);
  detect_mask_dtype<<<dim3(1), dim3(256), 0, stream>>>(M, flag);

  const bool prep = ws_size >= (size_t)64 + KBF_BYTES + VT_BYTES;
  short* Kbf = (short*)((char*)d_ws + 64);
  short* VT  = (short*)((char*)d_ws + 64 + KBF_BYTES);
  if (prep) {
    prep_k<<<dim3((B_ * H_ * S_ * D_) / (256 * 8)), dim3(256), 0, stream>>>(K, Kbf);
    prep_vt<<<dim3(B_ * H_ * (S_ / 64)), dim3(256), 0, stream>>>(V, VT);
    attn_fused<1><<<dim3(B_ * H_ * (S_ / QBLK)), dim3(NTHREADS), 0, stream>>>(
        Q, K, V, scale, M, flag, Kbf, VT, outC, outA);
  } else {
    attn_fused<0><<<dim3(B_ * H_ * (S_ / QBLK)), dim3(NTHREADS), 0, stream>>>(
        Q, K, V, scale, M, flag, Kbf, VT, outC, outA);
  }
}

// Round 5
// 1352.392 us; speedup vs baseline: 1.1544x; 1.1544x over previous
//
#include <hip/hip_runtime.h>
#include <stdint.h>

#define B_ 4
#define H_ 16
#define S_ 2048
#define D_ 64
#define QBLK 16
#define NTHREADS 512
#define NWAVES 8
#define KSLAB 256                    /* per-wave k coverage */
#define NWIN (KSLAB / 32)            /* 8 windows of 32 k */

typedef __attribute__((ext_vector_type(8))) short short8;
typedef __attribute__((ext_vector_type(4))) float float4v;
typedef __attribute__((ext_vector_type(4))) unsigned int uint4v;

static __device__ __forceinline__ short f2bf(float f) {
  uint32_t u = __builtin_bit_cast(uint32_t, f);
  u = (u + 0x7FFFu + ((u >> 16) & 1u)) >> 16;   // RNE
  return (short)u;
}
static __device__ __forceinline__ float bf2f(short s) {
  uint32_t u = ((uint32_t)(uint16_t)s) << 16;
  return __builtin_bit_cast(float, u);
}
static __device__ __forceinline__ uint32_t packbf(float lo, float hi) {
  return ((uint32_t)(uint16_t)f2bf(hi) << 16) | (uint16_t)f2bf(lo);
}
static __device__ __forceinline__ uint32_t nz4(uint32_t d) {
  uint32_t x = (d & 0x7F7F7F7Fu) + 0x7F7F7F7Fu;
  x = (x | d) & 0x80808080u;
  return x >> 7;
}
static __device__ __forceinline__ uint32_t nib(uint32_t d) {
  return ((nz4(d) * 0x01020408u) >> 24) & 0xFu;
}

#define KBF_BYTES ((size_t)64 * S_ * D_ * 2)
#define VT_BYTES  ((size_t)64 * S_ * D_ * 2)

__global__ void detect_mask_dtype(const uint8_t* __restrict__ m, uint32_t* flag) {
  uint32_t a = 0, b = 0;
  for (int i = threadIdx.x; i < 65536; i += 256) {
    uint8_t x = m[i];
    if (i & 3) a |= x; else b |= x;
  }
  uint32_t bits = (a ? 1u : 0u) | (b ? 2u : 0u);
  if (bits) atomicOr(flag, bits);
}

__global__ __launch_bounds__(256) void prep_k(const float* __restrict__ K,
                                              short* __restrict__ Kbf) {
  size_t base = ((size_t)blockIdx.x * 256 + threadIdx.x) * 8;
  float4v a = __builtin_nontemporal_load((const float4v*)(K + base));
  float4v b = __builtin_nontemporal_load((const float4v*)(K + base + 4));
  short8 o;
  o[0]=f2bf(a.x); o[1]=f2bf(a.y); o[2]=f2bf(a.z); o[3]=f2bf(a.w);
  o[4]=f2bf(b.x); o[5]=f2bf(b.y); o[6]=f2bf(b.z); o[7]=f2bf(b.w);
  *(short8*)(Kbf + base) = o;
}

__global__ __launch_bounds__(256) void prep_vt(const float* __restrict__ V,
                                               short* __restrict__ VT) {
  __shared__ short tile[64][72];
  int bh = blockIdx.x >> 5, k0 = (blockIdx.x & 31) * 64;
  const float* src = V + ((size_t)bh * S_ + k0) * D_;
  int t = threadIdx.x;
  int r = t >> 2, c0 = (t & 3) * 16;
#pragma unroll
  for (int j = 0; j < 4; ++j) {
    float4v f = __builtin_nontemporal_load((const float4v*)(src + (size_t)r * D_ + c0 + j * 4));
    tile[r][c0 + j*4 + 0] = f2bf(f.x);
    tile[r][c0 + j*4 + 1] = f2bf(f.y);
    tile[r][c0 + j*4 + 2] = f2bf(f.z);
    tile[r][c0 + j*4 + 3] = f2bf(f.w);
  }
  __syncthreads();
  int d = t >> 2, ks0 = (t & 3) * 16;
  short* dst = VT + (size_t)bh * D_ * S_ + (size_t)d * S_ + k0 + ks0;
#pragma unroll
  for (int half = 0; half < 2; ++half) {
    short8 o;
#pragma unroll
    for (int i = 0; i < 8; ++i) o[i] = tile[ks0 + half * 8 + i][d];
    *(short8*)(dst + half * 8) = o;
  }
}

template <int PREP>
__global__ __launch_bounds__(NTHREADS, 2) void attn_fused(
    const float* __restrict__ Q, const float* __restrict__ K,
    const float* __restrict__ V, const float* __restrict__ scale_p,
    const uint8_t* __restrict__ M, const uint32_t* __restrict__ flag,
    const short* __restrict__ Kbf, const short* __restrict__ VT,
    float* __restrict__ outC, float* __restrict__ outA)
{
  __shared__ uint32_t mbits[QBLK * 65];        // bit = masked
  __shared__ float lsum[QBLK];
  __shared__ float linv[QBLK];
  __shared__ float cbuf[QBLK * 65];
  __shared__ float tiles[NWAVES * 16 * 33];    // per-wave store-transpose tile

  // XCD-chunked bijective swizzle (8192 blocks, 8 XCDs, 1024 works each)
  const int bx  = (blockIdx.x & 7) * 1024 + (blockIdx.x >> 3);
  const int bh  = bx >> 7;                     // 128 q-tiles per (b,h)
  const int q0  = (bx & 127) * QBLK;

  const int tid  = threadIdx.x;
  const int w    = tid >> 6;                   // wave = k-slab 0..7
  const int lane = tid & 63;
  const int g    = lane >> 4;                  // 0..3
  const int c    = lane & 15;                  // 0..15
  const int kslab0 = w * KSLAB;

  const float scale = scale_p[0];
  const uint32_t fl = flag[0];

  const float* Qp = Q + (size_t)bh * S_ * D_;
  const short* Kbp = Kbf + (size_t)bh * S_ * D_;
  const short* VTp = VT + (size_t)bh * D_ * S_;
  const float* Kfp = K + (size_t)bh * S_ * D_;
  const float* Vfp = V + (size_t)bh * S_ * D_;

  // ---- prologue: mask bitmap (QBLK x 2048 bits) + zero reductions ----
  {
    const int row = tid >> 5;                  // 0..15
    const int w0  = (tid & 31) * 2;            // 2 words per thread
    if (fl == 3u) {                            // byte mask
      const uint8_t* mrow = M + ((size_t)bh * S_ + q0 + row) * (size_t)S_ + w0 * 32;
#pragma unroll
      for (int j = 0; j < 2; ++j) {
        uint4v a = __builtin_nontemporal_load((const uint4v*)(mrow + j * 32));
        uint4v b = __builtin_nontemporal_load((const uint4v*)(mrow + j * 32 + 16));
        uint32_t bits = nib(a.x) | (nib(a.y) << 4) | (nib(a.z) << 8)  | (nib(a.w) << 12)
                      | (nib(b.x) << 16) | (nib(b.y) << 20) | (nib(b.z) << 24) | (nib(b.w) << 28);
        mbits[row * 65 + w0 + j] = bits;
      }
    } else {                                   // 4-byte mask (int32 / float32)
      const uint32_t* mrow = (const uint32_t*)M + ((size_t)bh * S_ + q0 + row) * (size_t)S_ + w0 * 32;
#pragma unroll
      for (int j = 0; j < 2; ++j) {
        uint32_t bits = 0;
#pragma unroll
        for (int u = 0; u < 8; ++u) {
          uint4v wv = __builtin_nontemporal_load((const uint4v*)(mrow + j * 32 + u * 4));
          uint32_t nzb = (wv.x ? 1u : 0u) | (wv.y ? 2u : 0u) | (wv.z ? 4u : 0u) | (wv.w ? 8u : 0u);
          bits |= nzb << (u * 4);
        }
        mbits[row * 65 + w0 + j] = bits;
      }
    }
    for (int i = tid; i < QBLK * 65; i += NTHREADS) cbuf[i] = 0.0f;
    if (tid < QBLK) lsum[tid] = 0.0f;
  }
  __syncthreads();

  // ---- Q as B-frag: lane holds Q[q0+c][.] ----
  short8 qB[2];
#pragma unroll
  for (int h = 0; h < 2; ++h) {
    const float* qr = Qp + (size_t)(q0 + c) * D_ + h * 32 + g * 8;
    float4v a = *(const float4v*)qr;
    float4v b = *(const float4v*)(qr + 4);
    short8 f;
    f[0]=f2bf(a.x); f[1]=f2bf(a.y); f[2]=f2bf(a.z); f[3]=f2bf(a.w);
    f[4]=f2bf(b.x); f[5]=f2bf(b.y); f[6]=f2bf(b.z); f[7]=f2bf(b.w);
    qB[h] = f;
  }

  const uint32_t* mrowp = &mbits[c * 65 + (kslab0 >> 5)];
  const int srcA = ((2 * g) & 3) * 16 + c;
  const int srcB = srcA + 16;
  const bool hi = g >= 2;

  float rsv = 0.0f;
  float4v cacc[4];
#pragma unroll
  for (int nd = 0; nd < 4; ++nd) cacc[nd] = (float4v){0.f, 0.f, 0.f, 0.f};
  uint32_t es[NWIN][4];

  // ---- phase 1: swapped QK^T -> E in regs -> shuffle -> PV ----
#pragma unroll
  for (int win = 0; win < NWIN; ++win) {
    const int kwin = kslab0 + win * 32;
    float4v acc[2];
    acc[0] = (float4v){0.f,0.f,0.f,0.f};
    acc[1] = (float4v){0.f,0.f,0.f,0.f};
#pragma unroll
    for (int nb = 0; nb < 2; ++nb) {
      short8 a0, a1;
      if (PREP) {
        const short* kr = Kbp + (size_t)(kwin + nb * 16 + c) * D_ + g * 8;
        a0 = *(const short8*)kr;
        a1 = *(const short8*)(kr + 32);
      } else {
        const float* kr = Kfp + (size_t)(kwin + nb * 16 + c) * D_ + g * 8;
        float4v x0 = *(const float4v*)kr,        x1 = *(const float4v*)(kr + 4);
        float4v y0 = *(const float4v*)(kr + 32), y1 = *(const float4v*)(kr + 36);
        a0[0]=f2bf(x0.x); a0[1]=f2bf(x0.y); a0[2]=f2bf(x0.z); a0[3]=f2bf(x0.w);
        a0[4]=f2bf(x1.x); a0[5]=f2bf(x1.y); a0[6]=f2bf(x1.z); a0[7]=f2bf(x1.w);
        a1[0]=f2bf(y0.x); a1[1]=f2bf(y0.y); a1[2]=f2bf(y0.z); a1[3]=f2bf(y0.w);
        a1[4]=f2bf(y1.x); a1[5]=f2bf(y1.y); a1[6]=f2bf(y1.z); a1[7]=f2bf(y1.w);
      }
      acc[nb] = __builtin_amdgcn_mfma_f32_16x16x32_bf16(a0, qB[0], acc[nb], 0, 0, 0);
      acc[nb] = __builtin_amdgcn_mfma_f32_16x16x32_bf16(a1, qB[1], acc[nb], 0, 0, 0);
    }
    // mask + exp (lane's q = c; k = kwin + nb*16 + 4g + r)
    const uint32_t mw = mrowp[win];
    float ev[2][4];
#pragma unroll
    for (int nb = 0; nb < 2; ++nb)
#pragma unroll
      for (int r = 0; r < 4; ++r) {
        const uint32_t bit = (mw >> (nb * 16 + 4 * g + r)) & 1u;
        float e = bit ? 1.0f : __expf(acc[nb][r] * scale);
        ev[nb][r] = e;
        rsv += e;
      }
    es[win][0] = packbf(ev[0][0], ev[0][1]);
    es[win][1] = packbf(ev[0][2], ev[0][3]);
    es[win][2] = packbf(ev[1][0], ev[1][1]);
    es[win][3] = packbf(ev[1][2], ev[1][3]);

    // shuffle-transpose: lane(g,c) collects E[q=c][k = kwin + g*8 + 0..7]
    uint32_t x0 = __shfl(es[win][0], srcA), y0 = __shfl(es[win][2], srcA);
    uint32_t x1 = __shfl(es[win][1], srcA), y1 = __shfl(es[win][3], srcA);
    uint32_t x2 = __shfl(es[win][0], srcB), y2 = __shfl(es[win][2], srcB);
    uint32_t x3 = __shfl(es[win][1], srcB), y3 = __shfl(es[win][3], srcB);
    uint4v bb;
    bb.x = hi ? y0 : x0;
    bb.y = hi ? y1 : x1;
    bb.z = hi ? y2 : x2;
    bb.w = hi ? y3 : x3;
    const short8 bfrag = __builtin_bit_cast(short8, bb);

    // PV: C^T partial, A = V^T frag
#pragma unroll
    for (int nd = 0; nd < 4; ++nd) {
      short8 vA;
      if (PREP) {
        vA = *(const short8*)&VTp[(size_t)(nd * 16 + c) * S_ + kwin + g * 8];
      } else {
        const float* vc = Vfp + (size_t)(kwin + g * 8) * D_ + nd * 16 + c;
#pragma unroll
        for (int e = 0; e < 8; ++e) vA[e] = f2bf(vc[(size_t)e * D_]);
      }
      cacc[nd] = __builtin_amdgcn_mfma_f32_16x16x32_bf16(vA, bfrag, cacc[nd], 0, 0, 0);
    }
  }

  // ---- reductions ----
  rsv += __shfl_xor(rsv, 16);
  rsv += __shfl_xor(rsv, 32);
  if (lane < 16) atomicAdd(&lsum[lane], rsv);
#pragma unroll
  for (int nd = 0; nd < 4; ++nd)
#pragma unroll
    for (int r = 0; r < 4; ++r)
      atomicAdd(&cbuf[c * 65 + nd * 16 + 4 * g + r], cacc[nd][r]);
  __syncthreads();

  if (tid < QBLK) linv[tid] = 1.0f / lsum[tid];
  __syncthreads();

  // ---- context write ----
  if (tid < QBLK * D_ / 4) {
    const int row = tid >> 4, d0 = (tid & 15) * 4;
    const float inv = linv[row];
    float4v cv;
    cv.x = cbuf[row * 65 + d0 + 0] * inv;
    cv.y = cbuf[row * 65 + d0 + 1] * inv;
    cv.z = cbuf[row * 65 + d0 + 2] * inv;
    cv.w = cbuf[row * 65 + d0 + 3] * inv;
    __builtin_nontemporal_store(cv, (float4v*)&outC[((size_t)bh * S_ + q0 + row) * D_ + d0]);
  }

  // ---- phase 2: normalized attention stores (per-wave LDS transpose) ----
  const float linvq = linv[c];
  float* tile = &tiles[w * (16 * 33)];
  float* arowbase = outA + ((size_t)bh * S_ + q0) * (size_t)S_ + kslab0;
#pragma unroll
  for (int win = 0; win < NWIN; ++win) {
#pragma unroll
    for (int nb = 0; nb < 2; ++nb) {
      const uint32_t plo = es[win][nb * 2], phi = es[win][nb * 2 + 1];
      float* tr = &tile[c * 33 + nb * 16 + 4 * g];
      tr[0] = bf2f((short)(plo & 0xffff)) * linvq;
      tr[1] = bf2f((short)(plo >> 16))    * linvq;
      tr[2] = bf2f((short)(phi & 0xffff)) * linvq;
      tr[3] = bf2f((short)(phi >> 16))    * linvq;
    }
#pragma unroll
    for (int s = 0; s < 2; ++s) {
      const int row = s * 8 + (lane >> 3);
      const int col = (lane & 7) * 4;
      float4v v;
      v.x = tile[row * 33 + col + 0];
      v.y = tile[row * 33 + col + 1];
      v.z = tile[row * 33 + col + 2];
      v.w = tile[row * 33 + col + 3];
      __builtin_nontemporal_store(v, (float4v*)&arowbase[(size_t)row * S_ + win * 32 + col]);
    }
  }
}

extern "C" void kernel_launch(void* const* d_in, const int* in_sizes, int n_in,
                              void* d_out, int out_size, void* d_ws, size_t ws_size,
                              hipStream_t stream) {
  const float*   Q     = (const float*)d_in[0];
  const float*   K     = (const float*)d_in[1];
  const float*   V     = (const float*)d_in[2];
  const float*   scale = (const float*)d_in[3];
  const uint8_t* M     = (const uint8_t*)d_in[4];
  uint32_t* flag = (uint32_t*)d_ws;
  float* outC = (float*)d_out;
  float* outA = outC + (size_t)B_ * H_ * S_ * D_;

  hipMemsetAsync(flag, 0, 4, stream);
  detect_mask_dtype<<<dim3(1), dim3(256), 0, stream>>>(M, flag);

  const bool prep = ws_size >= (size_t)64 + KBF_BYTES + VT_BYTES;
  short* Kbf = (short*)((char*)d_ws + 64);
  short* VT  = (short*)((char*)d_ws + 64 + KBF_BYTES);
  if (prep) {
    prep_k<<<dim3((B_ * H_ * S_ * D_) / (256 * 8)), dim3(256), 0, stream>>>(K, Kbf);
    prep_vt<<<dim3(B_ * H_ * (S_ / 64)), dim3(256), 0, stream>>>(V, VT);
    attn_fused<1><<<dim3(B_ * H_ * (S_ / QBLK)), dim3(NTHREADS), 0, stream>>>(
        Q, K, V, scale, M, flag, Kbf, VT, outC, outA);
  } else {
    attn_fused<0><<<dim3(B_ * H_ * (S_ / QBLK)), dim3(NTHREADS), 0, stream>>>(
        Q, K, V, scale, M, flag, Kbf, VT, outC, outA);
  }
}